// Round 1
// baseline (489.256 us; speedup 1.0000x reference)
//
#include <hip/hip_runtime.h>
#include <hip/hip_bf16.h>

#define IN_F   4096
#define OUT_F  4096
#define M_TOT  8192
#define BK     64
#define NT     (IN_F / BK)      // 64 K-tiles

typedef short  short8  __attribute__((ext_vector_type(8)));
typedef float  floatx4 __attribute__((ext_vector_type(4)));

// fp32 -> bf16 round-to-nearest-even (inputs here are never NaN)
__device__ __forceinline__ unsigned short f2bf(float f) {
    union { float f; unsigned u; } v; v.f = f;
    unsigned r = v.u + 0x7FFFu + ((v.u >> 16) & 1u);
    return (unsigned short)(r >> 16);
}

__device__ __forceinline__ void load_lds16(const unsigned short* g, unsigned short* l) {
    __builtin_amdgcn_global_load_lds(
        (const __attribute__((address_space(1))) unsigned int*)g,
        (__attribute__((address_space(3))) unsigned int*)l, 16, 0, 0);
}

// ---------------- pass 1a: int4 dequant -> Wt[n][k] bf16 (verbatim from verified prep) ----------------
__global__ __launch_bounds__(256)
void dequant_kernel(const int* __restrict__ qw, const int* __restrict__ qz,
                    const float* __restrict__ sc, unsigned short* __restrict__ Wt) {
    __shared__ unsigned short T[64][136];
    const int t = threadIdx.x;
    const int n0  = (blockIdx.x & 63) * 64;
    const int g   = blockIdx.x >> 6;          // quant group, 0..31
    const int kp0 = g * 16;
    const int kp_l = t >> 4;
    const int n_l  = (t & 15) * 4;
    int4 q4 = *(const int4*)&qw[(size_t)(kp0 + kp_l) * OUT_F + n0 + n_l];
    #pragma unroll
    for (int j = 0; j < 4; ++j) {
        const int n = n0 + n_l + j;
        const unsigned z4 = (unsigned)qz[g * (OUT_F / 8) + (n >> 3)];
        const int   z = (int)((z4 >> (4 * (n & 7))) & 15u);
        const float s = sc[g * OUT_F + n];
        const unsigned q = ((const unsigned*)&q4)[j];
        short8 v;
        #pragma unroll
        for (int jj = 0; jj < 8; ++jj) {
            const int wi = (int)((q >> (4 * jj)) & 15u);
            v[jj] = (short)f2bf((float)(wi - z) * s);   // ref: (w-z)*s fp32, RNE->bf16
        }
        *(short8*)&T[n_l + j][kp_l * 8] = v;
    }
    __syncthreads();
    #pragma unroll
    for (int it = 0; it < 4; ++it) {
        const int p = t + it * 256;
        const int row = p >> 4, c = p & 15;
        short8 v = *(short8*)&T[row][c * 8];
        *(short8*)&Wt[(size_t)(n0 + row) * IN_F + (size_t)(kp0 + c) * 8] = v;
    }
}

// ---------------- pass 1b: x fp32 -> bf16 (verbatim from verified prep) ----------------
__global__ __launch_bounds__(256)
void conv_kernel(const float* __restrict__ x, unsigned short* __restrict__ xb) {
    const int t = threadIdx.x;
    size_t i = ((size_t)blockIdx.x * 256 + t) * 8;
    const float4* p = (const float4*)(x + i);
    float4 f0 = p[0], f1 = p[1];
    short8 v;
    v[0] = (short)f2bf(f0.x); v[1] = (short)f2bf(f0.y);
    v[2] = (short)f2bf(f0.z); v[3] = (short)f2bf(f0.w);
    v[4] = (short)f2bf(f1.x); v[5] = (short)f2bf(f1.y);
    v[6] = (short)f2bf(f1.z); v[7] = (short)f2bf(f1.w);
    *(short8*)(xb + i) = v;
}

// ---------------- pass 2: 256x256 8-wave, 4-phase/K-tile, counted-vmcnt bf16 GEMM ----------------
// LDS layout (per tile, per matrix): row r (0..255) = 8 packets of 8 bf16; packet p holds
// global k-packet kg = p ^ (r&7)  (same verified XOR swizzle as the R4 kernel).
// Staging: global_load_lds, linear LDS dest (wave-uniform base + lane*16B), pre-swizzled
// global source: row = rowbase + (lane>>3), kg = (lane&7)^(lane>>3)  (rowbase % 8 == 0).
// Units per K-tile (each = 2 issues/thread = 16 KB):
//   A-h0 rows {0-63,128-191}, A-h1 rows {64-127,192-255},
//   B-j0 rows {0-31,64-95,128-159,192-223}, B-j1 = +32.
// Phase order (kk,jh): P0=(0,0) P1=(0,1) P2=(1,0) P3=(1,1).
//   B-j0 last read at P2 -> t+2's B-j0 may be issued into CUR at P3 (after P2's barrier).
//   All t+1 units go to the other buffer (no region constraint).
// vmcnt(2) at end of each tile drains everything except t+2's B-j0 (2 loads in flight).

#define ISSUE_A(u,l,b) do { load_lds16(pA[u][l], &As[b][dA[u][l]]); pA[u][l] += BK; } while (0)
#define ISSUE_B(u,l,b) do { load_lds16(pB[u][l], &Bs[b][dB[u][l]]); pB[u][l] += BK; } while (0)

#define DS_A(b, xk) \
    _Pragma("unroll") \
    for (int i = 0; i < 8; ++i) \
        af[i] = *(const short8*)&As[b][(wm * 128 + i * 16 + l16) * BK + (xk)];

#define DS_B(b, jh, xk) \
    _Pragma("unroll") \
    for (int j = 0; j < 2; ++j) \
        bfv[j] = *(const short8*)&Bs[b][(wn * 64 + ((jh) * 2 + j) * 16 + l16) * BK + (xk)];

#define MFMA16(jh) \
    _Pragma("unroll") \
    for (int i = 0; i < 8; ++i) { \
        acc[i][(jh) * 2 + 0] = __builtin_amdgcn_mfma_f32_16x16x32_bf16(af[i], bfv[0], acc[i][(jh) * 2 + 0], 0, 0, 0); \
        acc[i][(jh) * 2 + 1] = __builtin_amdgcn_mfma_f32_16x16x32_bf16(af[i], bfv[1], acc[i][(jh) * 2 + 1], 0, 0, 0); \
    }

#define PH_MID \
    __builtin_amdgcn_s_barrier(); \
    asm volatile("s_waitcnt lgkmcnt(0)" ::: "memory"); \
    __builtin_amdgcn_sched_barrier(0); \
    __builtin_amdgcn_s_setprio(1);

#define PH_END \
    __builtin_amdgcn_s_setprio(0); \
    __builtin_amdgcn_s_barrier();

#define KTILE(CUR, NXT, I1, I2, VMW) \
    DS_A(CUR, xk0) DS_B(CUR, 0, xk0) \
    if (I1) { ISSUE_A(0, 0, NXT); ISSUE_A(0, 1, NXT); } \
    PH_MID MFMA16(0) PH_END \
    DS_B(CUR, 1, xk0) \
    if (I1) { ISSUE_A(1, 0, NXT); ISSUE_A(1, 1, NXT); } \
    PH_MID MFMA16(1) PH_END \
    DS_A(CUR, xk1) DS_B(CUR, 0, xk1) \
    if (I1) { ISSUE_B(1, 0, NXT); ISSUE_B(1, 1, NXT); } \
    PH_MID MFMA16(0) PH_END \
    DS_B(CUR, 1, xk1) \
    if (I2) { ISSUE_B(0, 0, CUR); ISSUE_B(0, 1, CUR); } \
    PH_MID MFMA16(1) \
    __builtin_amdgcn_s_setprio(0); \
    asm volatile("s_waitcnt " VMW ::: "memory"); \
    __builtin_amdgcn_s_barrier();

__global__ __launch_bounds__(512, 2)
void gemm256(const unsigned short* __restrict__ A,   // [M][K] bf16 (xb)
             const unsigned short* __restrict__ Bm,  // [N][K] bf16 (Wt)
             float* __restrict__ out) {
    __shared__ unsigned short As[2][256 * BK];   // 64 KB
    __shared__ unsigned short Bs[2][256 * BK];   // 64 KB

    const int tid  = threadIdx.x;
    const int lane = tid & 63;
    const int w    = tid >> 6;          // wave 0..7
    const int wm   = w >> 2;            // 0..1 (M)
    const int wn   = w & 3;             // 0..3 (N)
    const int l16  = lane & 15;
    const int quad = lane >> 4;

    // XCD-aware swizzle: 512 wgs, 512 % 8 == 0 -> simple bijective form
    const int bid = (int)blockIdx.x;
    const int swz = (bid & 7) * 64 + (bid >> 3);
    const int m0 = (swz >> 4) * 256;    // 32 M-tiles
    const int n0 = (swz & 15) * 256;    // 16 N-tiles

    const int rl   = lane >> 3;                  // row within 8-row chunk
    const int koff = ((lane & 7) ^ rl) * 8;      // pre-swizzled k-packet (elements)

    const unsigned short* pA[2][2];
    const unsigned short* pB[2][2];
    int dA[2][2], dB[2][2];
    #pragma unroll
    for (int u = 0; u < 2; ++u)
        #pragma unroll
        for (int l = 0; l < 2; ++l) {
            const int ra = u * 64 + l * 128 + w * 8;
            pA[u][l] = A + (size_t)(m0 + ra + rl) * IN_F + koff;
            dA[u][l] = ra * BK;
            const int rb = u * 32 + l * 128 + (w >> 2) * 64 + (w & 3) * 8;
            pB[u][l] = Bm + (size_t)(n0 + rb + rl) * IN_F + koff;
            dB[u][l] = rb * BK;
        }

    floatx4 acc[8][4];
    #pragma unroll
    for (int i = 0; i < 8; ++i)
        #pragma unroll
        for (int j = 0; j < 4; ++j)
            acc[i][j] = (floatx4){0.f, 0.f, 0.f, 0.f};

    const int xk0 = ((quad    ) ^ (l16 & 7)) * 8;   // kk=0 fragment offset
    const int xk1 = ((quad + 4) ^ (l16 & 7)) * 8;   // kk=1

    short8 af[8], bfv[2];

    // ---- prologue: tile0 all 4 units + tile1's B-j0 (the (T-2).P3 unit) ----
    ISSUE_A(0, 0, 0); ISSUE_A(0, 1, 0);
    ISSUE_A(1, 0, 0); ISSUE_A(1, 1, 0);
    ISSUE_B(1, 0, 0); ISSUE_B(1, 1, 0);
    ISSUE_B(0, 0, 0); ISSUE_B(0, 1, 0);
    ISSUE_B(0, 0, 1); ISSUE_B(0, 1, 1);     // tile1 B-j0 (k=64)
    asm volatile("s_waitcnt vmcnt(2)" ::: "memory");   // tile0 resident; 2 loads in flight
    __builtin_amdgcn_s_barrier();

    // ---- main loop: tiles 0..61 steady (counted vmcnt, never 0) ----
    for (int tt = 0; tt < NT / 2 - 1; ++tt) {
        KTILE(0, 1, true, true, "vmcnt(2)")
        KTILE(1, 0, true, true, "vmcnt(2)")
    }
    // ---- tails: tile 62 (stage tile63's nxt-buffer units), tile 63 ----
    KTILE(0, 1, true, false, "vmcnt(0)")
    KTILE(1, 0, false, false, "vmcnt(0)")

    // ---- epilogue: C/D layout col=lane&15, row=quad*4+reg (verified R2-R4); NT stores ----
    float* obase = out + (size_t)(m0 + wm * 128 + quad * 4) * OUT_F + n0 + wn * 64 + l16;
    #pragma unroll
    for (int i = 0; i < 8; ++i)
        #pragma unroll
        for (int j = 0; j < 4; ++j)
            #pragma unroll
            for (int r = 0; r < 4; ++r)
                __builtin_nontemporal_store(acc[i][j][r],
                    &obase[(size_t)(i * 16 + r) * OUT_F + j * 16]);
}

// ---------------- fallback: R2 fused kernel (verified correct) ----------------
#define BM     128
#define BN     128
#define KPAD   8
#define LDK    (BK + KPAD)
__global__ __launch_bounds__(256, 2)
void gptq_gemm_fused(const float* __restrict__ x,
                     const int*   __restrict__ qweight,
                     const int*   __restrict__ qzeros,
                     const float* __restrict__ scales,
                     float* __restrict__ out)
{
    __shared__ unsigned short As[BM][LDK];
    __shared__ unsigned short Bs[BN][LDK];
    const int tid  = threadIdx.x;
    const int lane = tid & 63;
    const int wave = tid >> 6;
    const int wm   = wave >> 1;
    const int wn   = wave & 1;
    const int l16  = lane & 15;
    const int quad = lane >> 4;
    const int n0 = blockIdx.x * BN;
    const int m0 = blockIdx.y * BM;

    floatx4 acc[4][4];
    #pragma unroll
    for (int i = 0; i < 4; ++i)
        #pragma unroll
        for (int j = 0; j < 4; ++j)
            acc[i][j] = (floatx4){0.f, 0.f, 0.f, 0.f};

    const int kgA = tid & 7;
    const int r0A = tid >> 3;
    const int bn   = tid & 127;
    const int pk0  = tid >> 7;
    const int gcol = n0 + bn;

    for (int kt = 0; kt < IN_F / BK; ++kt) {
        {
            const float* srcbase = x + (size_t)(m0 + r0A) * IN_F + kt * BK + kgA * 8;
            #pragma unroll
            for (int it = 0; it < 4; ++it) {
                const float4* p = (const float4*)(srcbase + (size_t)it * 32 * IN_F);
                float4 f0 = p[0]; float4 f1 = p[1];
                short8 v;
                v[0] = (short)f2bf(f0.x); v[1] = (short)f2bf(f0.y);
                v[2] = (short)f2bf(f0.z); v[3] = (short)f2bf(f0.w);
                v[4] = (short)f2bf(f1.x); v[5] = (short)f2bf(f1.y);
                v[6] = (short)f2bf(f1.z); v[7] = (short)f2bf(f1.w);
                *(short8*)&As[r0A + it * 32][kgA * 8] = v;
            }
        }
        {
            const int g = (kt * BK) >> 7;
            const unsigned qzv = (unsigned)qzeros[g * (OUT_F / 8) + (gcol >> 3)];
            const int   z = (int)((qzv >> (4 * (gcol & 7))) & 15u);
            const float s = scales[g * OUT_F + gcol];
            #pragma unroll
            for (int it = 0; it < 4; ++it) {
                const int pk = pk0 + it * 2;
                const unsigned q = (unsigned)qweight[(size_t)(kt * 8 + pk) * OUT_F + gcol];
                short8 v;
                #pragma unroll
                for (int j = 0; j < 8; ++j) {
                    const int wi = (int)((q >> (4 * j)) & 15u);
                    v[j] = (short)f2bf((float)(wi - z) * s);
                }
                *(short8*)&Bs[bn][pk * 8] = v;
            }
        }
        __syncthreads();
        #pragma unroll
        for (int kk = 0; kk < 2; ++kk) {
            const int ko = kk * 32 + quad * 8;
            short8 afr[4], bfr[4];
            #pragma unroll
            for (int i = 0; i < 4; ++i)
                afr[i] = *(const short8*)&As[wm * 64 + i * 16 + l16][ko];
            #pragma unroll
            for (int j = 0; j < 4; ++j)
                bfr[j] = *(const short8*)&Bs[wn * 64 + j * 16 + l16][ko];
            #pragma unroll
            for (int i = 0; i < 4; ++i)
                #pragma unroll
                for (int j = 0; j < 4; ++j)
                    acc[i][j] = __builtin_amdgcn_mfma_f32_16x16x32_bf16(afr[i], bfr[j], acc[i][j], 0, 0, 0);
        }
        __syncthreads();
    }
    float* obase = out + (size_t)(m0 + wm * 64 + quad * 4) * OUT_F + n0 + wn * 64 + l16;
    #pragma unroll
    for (int i = 0; i < 4; ++i)
        #pragma unroll
        for (int j = 0; j < 4; ++j)
            #pragma unroll
            for (int r = 0; r < 4; ++r)
                obase[(size_t)(i * 16 + r) * OUT_F + j * 16] = acc[i][j][r];
}

extern "C" void kernel_launch(void* const* d_in, const int* in_sizes, int n_in,
                              void* d_out, int out_size, void* d_ws, size_t ws_size,
                              hipStream_t stream) {
    const float* x       = (const float*)d_in[0];
    const int*   qweight = (const int*)d_in[1];
    const int*   qzeros  = (const int*)d_in[2];
    const float* scales  = (const float*)d_in[3];
    float* out = (float*)d_out;

    const size_t XB_BYTES = (size_t)M_TOT * IN_F * 2;   // 64 MB
    const size_t WT_BYTES = (size_t)OUT_F * IN_F * 2;   // 32 MB

    if (ws_size >= XB_BYTES + WT_BYTES) {
        unsigned short* xb = (unsigned short*)d_ws;
        unsigned short* Wt = (unsigned short*)((char*)d_ws + XB_BYTES);
        dequant_kernel<<<2048, 256, 0, stream>>>(qweight, qzeros, scales, Wt);
        conv_kernel<<<(M_TOT * IN_F) / (8 * 256), 256, 0, stream>>>(x, xb);
        gemm256<<<dim3(512), dim3(512), 0, stream>>>(xb, Wt, out);
    } else {
        gptq_gemm_fused<<<dim3(OUT_F / BN, M_TOT / BM), 256, 0, stream>>>(x, qweight, qzeros, scales, out);
    }
}

// Round 2
// 466.910 us; speedup vs baseline: 1.0479x; 1.0479x over previous
//
#include <hip/hip_runtime.h>
#include <hip/hip_bf16.h>

#define IN_F   4096
#define OUT_F  4096
#define M_TOT  8192
#define BK     64
#define NT     (IN_F / BK)      // 64 K-tiles

typedef short  short8  __attribute__((ext_vector_type(8)));
typedef float  floatx4 __attribute__((ext_vector_type(4)));

// fp32 -> bf16 round-to-nearest-even (inputs here are never NaN)
__device__ __forceinline__ unsigned short f2bf(float f) {
    union { float f; unsigned u; } v; v.f = f;
    unsigned r = v.u + 0x7FFFu + ((v.u >> 16) & 1u);
    return (unsigned short)(r >> 16);
}

__device__ __forceinline__ void load_lds16(const unsigned short* g, unsigned short* l) {
    __builtin_amdgcn_global_load_lds(
        (const __attribute__((address_space(1))) unsigned int*)g,
        (__attribute__((address_space(3))) unsigned int*)l, 16, 0, 0);
}

// ---------------- pass 1a: int4 dequant -> Wt[n][k] bf16 (verbatim, verified) ----------------
__global__ __launch_bounds__(256)
void dequant_kernel(const int* __restrict__ qw, const int* __restrict__ qz,
                    const float* __restrict__ sc, unsigned short* __restrict__ Wt) {
    __shared__ unsigned short T[64][136];
    const int t = threadIdx.x;
    const int n0  = (blockIdx.x & 63) * 64;
    const int g   = blockIdx.x >> 6;          // quant group, 0..31
    const int kp0 = g * 16;
    const int kp_l = t >> 4;
    const int n_l  = (t & 15) * 4;
    int4 q4 = *(const int4*)&qw[(size_t)(kp0 + kp_l) * OUT_F + n0 + n_l];
    #pragma unroll
    for (int j = 0; j < 4; ++j) {
        const int n = n0 + n_l + j;
        const unsigned z4 = (unsigned)qz[g * (OUT_F / 8) + (n >> 3)];
        const int   z = (int)((z4 >> (4 * (n & 7))) & 15u);
        const float s = sc[g * OUT_F + n];
        const unsigned q = ((const unsigned*)&q4)[j];
        short8 v;
        #pragma unroll
        for (int jj = 0; jj < 8; ++jj) {
            const int wi = (int)((q >> (4 * jj)) & 15u);
            v[jj] = (short)f2bf((float)(wi - z) * s);   // ref: (w-z)*s fp32, RNE->bf16
        }
        *(short8*)&T[n_l + j][kp_l * 8] = v;
    }
    __syncthreads();
    #pragma unroll
    for (int it = 0; it < 4; ++it) {
        const int p = t + it * 256;
        const int row = p >> 4, c = p & 15;
        short8 v = *(short8*)&T[row][c * 8];
        *(short8*)&Wt[(size_t)(n0 + row) * IN_F + (size_t)(kp0 + c) * 8] = v;
    }
}

// ---------------- pass 1b: x fp32 -> bf16 (verbatim, verified) ----------------
__global__ __launch_bounds__(256)
void conv_kernel(const float* __restrict__ x, unsigned short* __restrict__ xb) {
    const int t = threadIdx.x;
    size_t i = ((size_t)blockIdx.x * 256 + t) * 8;
    const float4* p = (const float4*)(x + i);
    float4 f0 = p[0], f1 = p[1];
    short8 v;
    v[0] = (short)f2bf(f0.x); v[1] = (short)f2bf(f0.y);
    v[2] = (short)f2bf(f0.z); v[3] = (short)f2bf(f0.w);
    v[4] = (short)f2bf(f1.x); v[5] = (short)f2bf(f1.y);
    v[6] = (short)f2bf(f1.z); v[7] = (short)f2bf(f1.w);
    *(short8*)(xb + i) = v;
}

// ---------------- pass 2: 256x256 8-wave GEMM, C-quadrant 4-phase/K-tile, deep counted vmcnt ----------------
// LDS: row r holds 8 packets; packet p = global k-packet p ^ (r&7)  (R1-verified swizzle).
// Staging unit (h,l): rows h*128 + l*64 + [0,64); 1 global_load_lds (16B/lane) per (h,l,tile).
//   global src: row += lane>>3, kg = (lane&7)^(lane>>3); LDS dest linear (wave base + lane*16B).
// Per tile t (CUR=t&1): phase p computes C-quadrant rows wm*128+p*32..+32 (16 MFMA).
//   P0: read B all 8 frags (held in regs, tile-lifetime) + A quad0 (4); ISSUE A(t+1) x4 -> NXT
//   P1: read A quad1; ISSUE B(t+2) h0 x2 -> CUR   (B-LDS of CUR dead after P0's seal)
//   P2: read A quad2; ISSUE B(t+2) h1 x2 -> CUR
//   P3: read A quad3; tile-end: s_waitcnt vmcnt(4)  (A(t+1) drained; B(t+2) x4 in flight)
// Latency budgets: A(t+1) ~3 phases, B(t+2) ~4-6 phases. No sched_barrier (m141 lesson).

#define ISSUE_A(h,l,b) do { load_lds16(pA[h][l], &As[b][dA[h][l]]); pA[h][l] += BK; } while (0)
#define ISSUE_B(h,l,b) do { load_lds16(pB[h][l], &Bs[b][dB[h][l]]); pB[h][l] += BK; } while (0)

#define READ_B(b) \
    _Pragma("unroll") \
    for (int j = 0; j < 4; ++j) { \
        bq[j][0] = *(const short8*)&Bs[b][boff[j][0]]; \
        bq[j][1] = *(const short8*)&Bs[b][boff[j][1]]; \
    }

#define READ_A(b, p) \
    _Pragma("unroll") \
    for (int i = 0; i < 2; ++i) { \
        af[i][0] = *(const short8*)&As[b][aoff[i][0] + (p) * 2048]; \
        af[i][1] = *(const short8*)&As[b][aoff[i][1] + (p) * 2048]; \
    }

#define MFMA16(p) \
    _Pragma("unroll") \
    for (int kk = 0; kk < 2; ++kk) \
        _Pragma("unroll") \
        for (int i = 0; i < 2; ++i) \
            _Pragma("unroll") \
            for (int j = 0; j < 4; ++j) \
                acc[(p) * 2 + i][j] = __builtin_amdgcn_mfma_f32_16x16x32_bf16(af[i][kk], bq[j][kk], acc[(p) * 2 + i][j], 0, 0, 0);

#define PH_MID \
    __builtin_amdgcn_s_barrier(); \
    asm volatile("s_waitcnt lgkmcnt(0)" ::: "memory"); \
    __builtin_amdgcn_s_setprio(1);

#define PH_END \
    __builtin_amdgcn_s_setprio(0); \
    __builtin_amdgcn_s_barrier();

#define KTILE(CUR, NXT, I1, I2, VMW) \
    READ_B(CUR) \
    READ_A(CUR, 0) \
    if (I1) { ISSUE_A(0, 0, NXT); ISSUE_A(0, 1, NXT); ISSUE_A(1, 0, NXT); ISSUE_A(1, 1, NXT); } \
    asm volatile("s_waitcnt lgkmcnt(8)" ::: "memory"); \
    PH_MID MFMA16(0) PH_END \
    READ_A(CUR, 1) \
    if (I2) { ISSUE_B(0, 0, CUR); ISSUE_B(0, 1, CUR); } \
    PH_MID MFMA16(1) PH_END \
    READ_A(CUR, 2) \
    if (I2) { ISSUE_B(1, 0, CUR); ISSUE_B(1, 1, CUR); } \
    PH_MID MFMA16(2) PH_END \
    READ_A(CUR, 3) \
    PH_MID MFMA16(3) \
    __builtin_amdgcn_s_setprio(0); \
    asm volatile("s_waitcnt " VMW ::: "memory"); \
    __builtin_amdgcn_s_barrier();

__global__ __launch_bounds__(512, 2)
void gemm256(const unsigned short* __restrict__ A,   // [M][K] bf16 (xb)
             const unsigned short* __restrict__ Bm,  // [N][K] bf16 (Wt)
             float* __restrict__ out) {
    __shared__ unsigned short As[2][256 * BK];   // 64 KB
    __shared__ unsigned short Bs[2][256 * BK];   // 64 KB

    const int tid  = threadIdx.x;
    const int lane = tid & 63;
    const int w    = tid >> 6;          // wave 0..7
    const int wm   = w >> 2;            // 0..1 (M)
    const int wn   = w & 3;             // 0..3 (N)
    const int l16  = lane & 15;
    const int quad = lane >> 4;

    // XCD-aware swizzle: 512 wgs, 512 % 8 == 0 -> simple bijective form
    const int bid = (int)blockIdx.x;
    const int swz = (bid & 7) * 64 + (bid >> 3);
    const int m0 = (swz >> 4) * 256;    // 32 M-tiles
    const int n0 = (swz & 15) * 256;    // 16 N-tiles

    const int rl   = lane >> 3;                  // row within 8-row chunk
    const int koff = ((lane & 7) ^ rl) * 8;      // pre-swizzled k-packet (elements)

    const unsigned short* pA[2][2];
    const unsigned short* pB[2][2];
    int dA[2][2], dB[2][2];
    #pragma unroll
    for (int h = 0; h < 2; ++h)
        #pragma unroll
        for (int l = 0; l < 2; ++l) {
            const int rr = h * 128 + l * 64 + w * 8;
            pA[h][l] = A  + (size_t)(m0 + rr + rl) * IN_F + koff;
            pB[h][l] = Bm + (size_t)(n0 + rr + rl) * IN_F + koff;
            dA[h][l] = rr * BK;
            dB[h][l] = rr * BK;
        }

    floatx4 acc[8][4];
    #pragma unroll
    for (int i = 0; i < 8; ++i)
        #pragma unroll
        for (int j = 0; j < 4; ++j)
            acc[i][j] = (floatx4){0.f, 0.f, 0.f, 0.f};

    // fragment LDS offsets (elements); row&7 == l16&7 for all frag rows (row bases are x16)
    int aoff[2][2], boff[4][2];
    #pragma unroll
    for (int kk = 0; kk < 2; ++kk) {
        #pragma unroll
        for (int i = 0; i < 2; ++i)
            aoff[i][kk] = ((wm * 128 + i * 16 + l16) * 8 + ((quad + kk * 4) ^ (l16 & 7))) * 8;
        #pragma unroll
        for (int j = 0; j < 4; ++j)
            boff[j][kk] = ((wn * 64 + j * 16 + l16) * 8 + ((quad + kk * 4) ^ (l16 & 7))) * 8;
    }

    short8 af[2][2], bq[4][2];

    // ---- prologue: A(0), B(0) -> buf0; B(1) -> buf1; drain tile0, keep B(1) in flight ----
    ISSUE_A(0, 0, 0); ISSUE_A(0, 1, 0); ISSUE_A(1, 0, 0); ISSUE_A(1, 1, 0);
    ISSUE_B(0, 0, 0); ISSUE_B(0, 1, 0); ISSUE_B(1, 0, 0); ISSUE_B(1, 1, 0);
    ISSUE_B(0, 0, 1); ISSUE_B(0, 1, 1); ISSUE_B(1, 0, 1); ISSUE_B(1, 1, 1);
    asm volatile("s_waitcnt vmcnt(4)" ::: "memory");
    __builtin_amdgcn_s_barrier();

    // ---- main loop: tiles 0..61 steady (vmcnt(4), never 0) ----
    for (int tt = 0; tt < NT / 2 - 1; ++tt) {
        KTILE(0, 1, true, true, "vmcnt(4)")
        KTILE(1, 0, true, true, "vmcnt(4)")
    }
    // ---- tails: tile 62 stages A(63) only; tile 63 stages nothing ----
    KTILE(0, 1, true, false, "vmcnt(0)")
    KTILE(1, 0, false, false, "vmcnt(0)")

    // ---- epilogue: C/D layout col=lane&15, row=quad*4+reg (verified R2-R4); NT stores ----
    float* obase = out + (size_t)(m0 + wm * 128 + quad * 4) * OUT_F + n0 + wn * 64 + l16;
    #pragma unroll
    for (int i = 0; i < 8; ++i)
        #pragma unroll
        for (int j = 0; j < 4; ++j)
            #pragma unroll
            for (int r = 0; r < 4; ++r)
                __builtin_nontemporal_store(acc[i][j][r],
                    &obase[(size_t)(i * 16 + r) * OUT_F + j * 16]);
}

// ---------------- fallback: R2 fused kernel (verified correct) ----------------
#define BM     128
#define BN     128
#define KPAD   8
#define LDK    (BK + KPAD)
__global__ __launch_bounds__(256, 2)
void gptq_gemm_fused(const float* __restrict__ x,
                     const int*   __restrict__ qweight,
                     const int*   __restrict__ qzeros,
                     const float* __restrict__ scales,
                     float* __restrict__ out)
{
    __shared__ unsigned short As[BM][LDK];
    __shared__ unsigned short Bs[BN][LDK];
    const int tid  = threadIdx.x;
    const int lane = tid & 63;
    const int wave = tid >> 6;
    const int wm   = wave >> 1;
    const int wn   = wave & 1;
    const int l16  = lane & 15;
    const int quad = lane >> 4;
    const int n0 = blockIdx.x * BN;
    const int m0 = blockIdx.y * BM;

    floatx4 acc[4][4];
    #pragma unroll
    for (int i = 0; i < 4; ++i)
        #pragma unroll
        for (int j = 0; j < 4; ++j)
            acc[i][j] = (floatx4){0.f, 0.f, 0.f, 0.f};

    const int kgA = tid & 7;
    const int r0A = tid >> 3;
    const int bn   = tid & 127;
    const int pk0  = tid >> 7;
    const int gcol = n0 + bn;

    for (int kt = 0; kt < IN_F / BK; ++kt) {
        {
            const float* srcbase = x + (size_t)(m0 + r0A) * IN_F + kt * BK + kgA * 8;
            #pragma unroll
            for (int it = 0; it < 4; ++it) {
                const float4* p = (const float4*)(srcbase + (size_t)it * 32 * IN_F);
                float4 f0 = p[0]; float4 f1 = p[1];
                short8 v;
                v[0] = (short)f2bf(f0.x); v[1] = (short)f2bf(f0.y);
                v[2] = (short)f2bf(f0.z); v[3] = (short)f2bf(f0.w);
                v[4] = (short)f2bf(f1.x); v[5] = (short)f2bf(f1.y);
                v[6] = (short)f2bf(f1.z); v[7] = (short)f2bf(f1.w);
                *(short8*)&As[r0A + it * 32][kgA * 8] = v;
            }
        }
        {
            const int g = (kt * BK) >> 7;
            const unsigned qzv = (unsigned)qzeros[g * (OUT_F / 8) + (gcol >> 3)];
            const int   z = (int)((qzv >> (4 * (gcol & 7))) & 15u);
            const float s = scales[g * OUT_F + gcol];
            #pragma unroll
            for (int it = 0; it < 4; ++it) {
                const int pk = pk0 + it * 2;
                const unsigned q = (unsigned)qweight[(size_t)(kt * 8 + pk) * OUT_F + gcol];
                short8 v;
                #pragma unroll
                for (int j = 0; j < 8; ++j) {
                    const int wi = (int)((q >> (4 * j)) & 15u);
                    v[j] = (short)f2bf((float)(wi - z) * s);
                }
                *(short8*)&Bs[bn][pk * 8] = v;
            }
        }
        __syncthreads();
        #pragma unroll
        for (int kk = 0; kk < 2; ++kk) {
            const int ko = kk * 32 + quad * 8;
            short8 afr[4], bfr[4];
            #pragma unroll
            for (int i = 0; i < 4; ++i)
                afr[i] = *(const short8*)&As[wm * 64 + i * 16 + l16][ko];
            #pragma unroll
            for (int j = 0; j < 4; ++j)
                bfr[j] = *(const short8*)&Bs[wn * 64 + j * 16 + l16][ko];
            #pragma unroll
            for (int i = 0; i < 4; ++i)
                #pragma unroll
                for (int j = 0; j < 4; ++j)
                    acc[i][j] = __builtin_amdgcn_mfma_f32_16x16x32_bf16(afr[i], bfr[j], acc[i][j], 0, 0, 0);
        }
        __syncthreads();
    }
    float* obase = out + (size_t)(m0 + wm * 64 + quad * 4) * OUT_F + n0 + wn * 64 + l16;
    #pragma unroll
    for (int i = 0; i < 4; ++i)
        #pragma unroll
        for (int j = 0; j < 4; ++j)
            #pragma unroll
            for (int r = 0; r < 4; ++r)
                obase[(size_t)(i * 16 + r) * OUT_F + j * 16] = acc[i][j][r];
}

extern "C" void kernel_launch(void* const* d_in, const int* in_sizes, int n_in,
                              void* d_out, int out_size, void* d_ws, size_t ws_size,
                              hipStream_t stream) {
    const float* x       = (const float*)d_in[0];
    const int*   qweight = (const int*)d_in[1];
    const int*   qzeros  = (const int*)d_in[2];
    const float* scales  = (const float*)d_in[3];
    float* out = (float*)d_out;

    const size_t XB_BYTES = (size_t)M_TOT * IN_F * 2;   // 64 MB
    const size_t WT_BYTES = (size_t)OUT_F * IN_F * 2;   // 32 MB

    if (ws_size >= XB_BYTES + WT_BYTES) {
        unsigned short* xb = (unsigned short*)d_ws;
        unsigned short* Wt = (unsigned short*)((char*)d_ws + XB_BYTES);
        dequant_kernel<<<2048, 256, 0, stream>>>(qweight, qzeros, scales, Wt);
        conv_kernel<<<(M_TOT * IN_F) / (8 * 256), 256, 0, stream>>>(x, xb);
        gemm256<<<dim3(512), dim3(512), 0, stream>>>(xb, Wt, out);
    } else {
        gptq_gemm_fused<<<dim3(OUT_F / BN, M_TOT / BM), 256, 0, stream>>>(x, qweight, qzeros, scales, out);
    }
}